// Round 5
// baseline (142.746 us; speedup 1.0000x reference)
//
#include <hip/hip_runtime.h>

#define NB 128
#define NTOK 201

// One block per (e, batch): 640 blocks x 1024 threads (16 row-groups x 64 col-groups).
// u^T <- u^T * att_e[l], l = 10..0, u0 = row 0 of att_e[11] (x row e, gathered cols).
// Padded-col space: p = xcol - (lo-3), valid window p in [3, M+2), e-slot at p=4*W4.
// Each row-group rg uses its own 16B-aligned start col C_rg (row stride 16*201 = 0 mod 4),
// shift undone in the LDS reduction.
__global__ __launch_bounds__(1024) void part_att_kernel(
    const float* __restrict__ x, float* __restrict__ out)
{
    const int bid = blockIdx.x;
    const int e   = bid % 5;
    const int b   = bid / 5;

    int lo, hi;
    if      (e == 0) { lo = 5;   hi = 201; }
    else if (e == 1) { lo = 5;   hi = 201; }
    else if (e == 2) { lo = 5;   hi = 103; }
    else if (e == 3) { lo = 54;  hi = 152; }
    else             { lo = 103; hi = 201; }
    const int M     = 1 + hi - lo;          // 197 or 99
    const int W4    = (M + 5) / 4;          // 50 or 26 float4 col-groups
    const int eslot = 4 * W4;               // padded slot of the e-column

    const int tid = threadIdx.x;
    const int g   = tid & 63;               // col-group
    const int rg  = tid >> 6;               // row-group 0..15

    __shared__ float u[2][212];
    __shared__ float part[16][212];
    __shared__ float rv[256];
    __shared__ int   ri[256];

    const size_t plane = (size_t)NTOK * NTOK;
    const float* xb  = x + (size_t)b * plane;
    const float* L11 = xb + (size_t)(11 * NB) * plane + (size_t)e * NTOK;

    // per-row-group aligned start col: global float offset (b + xrow + col) % 4 == 0
    // for xrow = lo-1+r, r === rg (mod 16)
    const int trg = (b + 2 * lo - 1 + rg) & 3;
    const int C   = lo - trg;               // in [lo-3, lo], >= 2

    // init u0
    if (tid <= eslot) {
        float v = 0.f;
        if (tid == eslot)               v = L11[e];
        else if (tid >= 3 && tid < M + 2) v = L11[lo - 3 + tid];
        u[0][tid] = v;
    }
    __syncthreads();

    int cur = 0;
    for (int l = 10; l >= 0; --l) {
        const float* A = xb + (size_t)(l * NB) * plane;
        const float* U = u[cur];
        if (g < W4) {
            float4 acc0 = make_float4(0.f, 0.f, 0.f, 0.f);
            float4 acc1 = make_float4(0.f, 0.f, 0.f, 0.f);
            int r = rg;
            if (rg == 0) {
                // att row 0 -> x row e (different alignment class: scalar x4)
                const float w = U[eslot];
                const float* p0 = A + (size_t)e * NTOK + C + 4 * g;
                acc0.x = w * p0[0]; acc0.y = w * p0[1];
                acc0.z = w * p0[2]; acc0.w = w * p0[3];
                r = 16;
            }
            const float* rp = A + (size_t)(lo - 1 + r) * NTOK + C + 4 * g;
            const size_t step = (size_t)16 * NTOK;
            for (; r + 16 < M; r += 32) {
                const float4 v0 = *(const float4*)rp;
                const float4 v1 = *(const float4*)(rp + step);
                const float w0 = U[r + 2];
                const float w1 = U[r + 18];
                acc0.x += w0 * v0.x; acc0.y += w0 * v0.y;
                acc0.z += w0 * v0.z; acc0.w += w0 * v0.w;
                acc1.x += w1 * v1.x; acc1.y += w1 * v1.y;
                acc1.z += w1 * v1.z; acc1.w += w1 * v1.w;
                rp += 2 * step;
            }
            for (; r < M; r += 16) {
                const float4 v0 = *(const float4*)rp;
                const float w0 = U[r + 2];
                acc0.x += w0 * v0.x; acc0.y += w0 * v0.y;
                acc0.z += w0 * v0.z; acc0.w += w0 * v0.w;
                rp += step;
            }
            acc0.x += acc1.x; acc0.y += acc1.y; acc0.z += acc1.z; acc0.w += acc1.w;
            *(float4*)&part[rg][4 * g] = acc0;      // 16B-aligned LDS store
        } else if (g == W4) {
            // the e-column (att col 0): scalar chain
            float s = 0.f;
            int r = rg;
            if (rg == 0) { s = U[eslot] * A[(size_t)e * NTOK + e]; r = 16; }
            const float* rp = A + (size_t)(lo - 1 + r) * NTOK + e;
            for (; r < M; r += 16) { s += U[r + 2] * rp[0]; rp += (size_t)16 * NTOK; }
            part[rg][eslot] = s;
        }
        __syncthreads();
        // reduce 16 row-groups -> new u (zero-mask padding/garbage cols)
        if (tid <= eslot) {
            float s = 0.f;
            if (tid == eslot) {
                #pragma unroll
                for (int q = 0; q < 16; ++q) s += part[q][eslot];
            } else if (tid >= 3 && tid < M + 2) {
                #pragma unroll
                for (int q = 0; q < 16; ++q) {
                    const int tq = (b + 2 * lo - 1 + q) & 3;
                    s += part[q][tid - 3 + tq];     // undo per-rg col shift
                }
            }
            u[1 - cur][tid] = s;
        }
        __syncthreads();
        cur ^= 1;
    }

    // max + argmax over p in [3, M+2)  (p-order == att-col order -> first-occurrence ties ok)
    if (tid < 256) {
        float v = -INFINITY; int idx = 0x7fffffff;
        if (tid >= 3 && tid < M + 2) { v = u[cur][tid]; idx = tid; }
        rv[tid] = v; ri[tid] = idx;
    }
    __syncthreads();
    for (int s = 128; s > 0; s >>= 1) {
        if (tid < s) {
            const float v2 = rv[tid + s]; const int i2 = ri[tid + s];
            if (v2 > rv[tid] || (v2 == rv[tid] && i2 < ri[tid])) {
                rv[tid] = v2; ri[tid] = i2;
            }
        }
        __syncthreads();
    }

    if (tid == 0) {
        // ref index = (j-1) + lo = xcol = lo - 3 + p
        out[e * NB + b]       = rv[0];
        out[640 + e * NB + b] = (float)(lo - 3 + ri[0]);
    }
}

extern "C" void kernel_launch(void* const* d_in, const int* in_sizes, int n_in,
                              void* d_out, int out_size, void* d_ws, size_t ws_size,
                              hipStream_t stream) {
    (void)in_sizes; (void)n_in; (void)d_ws; (void)ws_size; (void)out_size;
    const float* x = (const float*)d_in[0];
    float* out = (float*)d_out;
    part_att_kernel<<<dim3(640), dim3(1024), 0, stream>>>(x, out);
}

// Round 6
// 92.890 us; speedup vs baseline: 1.5367x; 1.5367x over previous
//
#include <hip/hip_runtime.h>

#define NB 128
#define NTOK 201

// u^T <- u^T * att_e[l], l = 10..0, u0 = row 0 of att_e[11].
// Padded-col space: p = xcol - (lo-3); valid p in [3, M+2); e-column at p = 4*W4.
// Per-row-group 16B-aligned start col C_rg (addr === b + xrow + col mod 4, and the
// row stride RG*201 === 0 mod 4), shift undone in the LDS reduction.
template<int GSH, int RG, int M>
__device__ __forceinline__ void chain(
    const float* __restrict__ xb, float* __restrict__ out,
    const int e, const int b, const int lo,
    float (*u)[212], float (*part)[212], float* rv, int* rix)
{
    constexpr int GN    = 1 << GSH;       // col-groups
    constexpr int W4    = (M + 5) / 4;    // active float4 col-groups
    constexpr int ESLOT = 4 * W4;         // padded slot of the e-column

    const int tid = threadIdx.x;
    const int g   = tid & (GN - 1);
    const int rg  = tid >> GSH;           // 0..RG-1

    const size_t plane = (size_t)NTOK * NTOK;
    const float* L11 = xb + (size_t)(11 * NB) * plane + (size_t)e * NTOK;

    const int trg = (b + 2 * lo - 1 + rg) & 3;
    const int C   = lo - trg;             // 16B-aligned start col for this rg class

    if (tid <= ESLOT) {
        float v = 0.f;
        if (tid == ESLOT)                 v = L11[e];
        else if (tid >= 3 && tid < M + 2) v = L11[lo - 3 + tid];
        u[0][tid] = v;
    }
    __syncthreads();

    int cur = 0;
    for (int l = 10; l >= 0; --l) {
        const float* A = xb + (size_t)(l * NB) * plane;
        const float* U = u[cur];
        if (g < W4) {
            float4 acc0 = make_float4(0.f, 0.f, 0.f, 0.f);
            float4 acc1 = make_float4(0.f, 0.f, 0.f, 0.f);
            int r = rg;
            if (rg == 0) {                // att row 0 -> x row e (scalar x4 head)
                const float w = U[ESLOT];
                const float* p0 = A + (size_t)e * NTOK + C + 4 * g;
                acc0.x = w * p0[0]; acc0.y = w * p0[1];
                acc0.z = w * p0[2]; acc0.w = w * p0[3];
                r = RG;
            }
            const float* rp = A + (size_t)(lo - 1 + r) * NTOK + C + 4 * g;
            const size_t step = (size_t)RG * NTOK;
            for (; r + RG < M; r += 2 * RG) {
                const float4 v0 = *(const float4*)rp;
                const float4 v1 = *(const float4*)(rp + step);
                const float w0 = U[r + 2];
                const float w1 = U[r + RG + 2];
                acc0.x += w0 * v0.x; acc0.y += w0 * v0.y;
                acc0.z += w0 * v0.z; acc0.w += w0 * v0.w;
                acc1.x += w1 * v1.x; acc1.y += w1 * v1.y;
                acc1.z += w1 * v1.z; acc1.w += w1 * v1.w;
                rp += 2 * step;
            }
            for (; r < M; r += RG) {
                const float4 v0 = *(const float4*)rp;
                const float w0 = U[r + 2];
                acc0.x += w0 * v0.x; acc0.y += w0 * v0.y;
                acc0.z += w0 * v0.z; acc0.w += w0 * v0.w;
                rp += step;
            }
            acc0.x += acc1.x; acc0.y += acc1.y;
            acc0.z += acc1.z; acc0.w += acc1.w;
            *(float4*)&part[rg][4 * g] = acc0;
        } else if (g == W4) {             // the e-column (att col 0)
            float s = 0.f;
            int r = rg;
            if (rg == 0) { s = U[ESLOT] * A[(size_t)e * NTOK + e]; r = RG; }
            const float* rp = A + (size_t)(lo - 1 + r) * NTOK + e;
            for (; r < M; r += RG) { s += U[r + 2] * rp[0]; rp += (size_t)RG * NTOK; }
            part[rg][ESLOT] = s;
        }
        __syncthreads();
        if (tid <= ESLOT) {               // reduce RG row-groups -> new u
            float s = 0.f;
            if (tid == ESLOT) {
                #pragma unroll
                for (int q = 0; q < RG; ++q) s += part[q][ESLOT];
            } else if (tid >= 3 && tid < M + 2) {
                #pragma unroll
                for (int q = 0; q < RG; ++q) {
                    const int tq = (b + 2 * lo - 1 + q) & 3;
                    s += part[q][tid - 3 + tq];   // undo per-rg col shift
                }
            }
            u[1 - cur][tid] = s;
        }
        __syncthreads();
        cur ^= 1;
    }

    // max + argmax over p in [3, M+2); p ascending == att-col ascending (ties ok)
    if (tid < 256) {
        float v = -INFINITY; int idx = 0x7fffffff;
        if (tid >= 3 && tid < M + 2) { v = u[cur][tid]; idx = tid; }
        rv[tid] = v; rix[tid] = idx;
    }
    __syncthreads();
    for (int s = 128; s > 0; s >>= 1) {
        if (tid < s) {
            const float v2 = rv[tid + s]; const int i2 = rix[tid + s];
            if (v2 > rv[tid] || (v2 == rv[tid] && i2 < rix[tid])) {
                rv[tid] = v2; rix[tid] = i2;
            }
        }
        __syncthreads();
    }
    if (tid == 0) {
        out[e * NB + b]       = rv[0];
        out[640 + e * NB + b] = (float)(lo - 3 + rix[0]);   // = (j-1) + lo
    }
}

// Grid 640 x 1024. bid = 128*e + b  =>  bid%8 = b%8: all 5 chains of a batch land
// on the SAME XCD (shared L2 dedups the overlapping plane reads), and dispatch
// order gives each CU ~1 heavy + ~1 light block.
__global__ __launch_bounds__(1024) void part_att_kernel(
    const float* __restrict__ x, float* __restrict__ out)
{
    __shared__ float u[2][212];
    __shared__ float part[32][212];
    __shared__ float rv[256];
    __shared__ int   rix[256];

    const int bid = blockIdx.x;
    const int e   = bid >> 7;
    const int b   = bid & 127;
    const float* xb = x + (size_t)b * ((size_t)NTOK * NTOK);

    if (e < 2) {
        chain<6, 16, 197>(xb, out, e, b, 5, u, part, rv, rix);
    } else {
        const int lo = (e == 2) ? 5 : (e == 3) ? 54 : 103;
        chain<5, 32, 99>(xb, out, e, b, lo, u, part, rv, rix);
    }
}

extern "C" void kernel_launch(void* const* d_in, const int* in_sizes, int n_in,
                              void* d_out, int out_size, void* d_ws, size_t ws_size,
                              hipStream_t stream) {
    (void)in_sizes; (void)n_in; (void)d_ws; (void)ws_size; (void)out_size;
    const float* x = (const float*)d_in[0];
    float* out = (float*)d_out;
    part_att_kernel<<<dim3(640), dim3(1024), 0, stream>>>(x, out);
}

// Round 7
// 89.718 us; speedup vs baseline: 1.5911x; 1.0354x over previous
//
#include <hip/hip_runtime.h>

#define NB 128
#define NTOK 201
#define EW 210   // u-slot holding the att-col-0 (e-column) weight

// Publish LDS writes across a barrier WITHOUT draining vmcnt: global loads
// issued before this stay in flight (unlike __syncthreads, which emits
// s_waitcnt vmcnt(0) and kills the pipeline overlap).
__device__ __forceinline__ void lds_barrier() {
    asm volatile("s_waitcnt lgkmcnt(0)" ::: "memory");
    __builtin_amdgcn_s_barrier();
}

// u^T <- u^T * att_e[l], l = 10..0, u0 = row 0 of att_e[11].
// Padded-col space p = xcol - (lo-3): valid p in [3, M+2); e-weight at u[EW].
// 1024 threads = 64 col-groups (g) x 16 row-groups (rg). Per-rg 16B-aligned
// start col C_rg ((b+row+col)%4==0; row stride 16*201 === 0 mod 4); the per-rg
// column shift is undone in the LDS reduction. Rows r=rg+16k with r>=M are
// clamped in-class (r-16) and auto-masked by zero weights u[r+2]=0.
template<int M, int K0, int K1, int K2>
__device__ __forceinline__ void chain_pipe(
    const float* __restrict__ xb, float* __restrict__ out,
    const int e, const int b, const int lo,
    float (*u)[212], float (*part)[212], float* rv, int* rix)
{
    constexpr int NK = K0 + K1 + K2;      // rows per thread = ceil(M/16)
    constexpr int W4 = (M + 5) / 4;       // active float4 col-groups (50 / 26)

    const int tid = threadIdx.x;
    const int g   = tid & 63;
    const int rg  = tid >> 6;             // 0..15

    const size_t plane = (size_t)NTOK * NTOK;
    const float* L11 = xb + (size_t)(11 * NB) * plane + (size_t)e * NTOK;

    const int trg = (b + 2 * lo - 1 + rg) & 3;
    const int C   = lo - trg;             // 16B-aligned start col for this rg

    // per-k row offsets (floats), clamped in-class for r >= M
    int roff[NK];
    #pragma unroll
    for (int k = 0; k < NK; ++k) {
        const int r = rg + 16 * k;
        roff[k] = 16 * NTOK * k - ((r >= M) ? 16 * NTOK : 0);
    }

    // init u: zeros in both buffers, then valid slots of buffer 0
    if (tid < 212) { u[0][tid] = 0.f; u[1][tid] = 0.f; }
    if (tid >= 3 && tid < M + 2) u[0][tid] = L11[lo - 3 + tid];
    if (tid == EW)               u[0][tid] = L11[e];
    __syncthreads();

    const int rowcol_f = (lo - 1 + rg) * NTOK + C + 4 * g;
    const int rowcol_e = (lo - 1 + rg) * NTOK + e;

    const float* A = xb + (size_t)(10 * NB) * plane;

    float4 b0[K0], b1[K1], b2[K2];
    float  s0[K0], s1[K1], s2[K2];

    // prologue: issue chunk0 of layer 10
    if (g < W4) {
        const float* fb = A + rowcol_f;
        #pragma unroll
        for (int k = 0; k < K0; ++k) b0[k] = *(const float4*)(fb + roff[k]);
    } else if (g == W4) {
        const float* ep = A + rowcol_e;
        #pragma unroll
        for (int k = 0; k < K0; ++k) s0[k] = ep[roff[k]];
    }

    int cur = 0;
    for (int l = 10; l >= 0; --l) {
        // ---- reduce part (layer l+1's FMAs) -> u(l); overlaps chunk0 flight ----
        if (l < 10) {
            if (tid >= 3 && tid < M + 2) {
                float s = 0.f;
                #pragma unroll
                for (int q = 0; q < 16; ++q) {
                    const int tq = (b + 2 * lo - 1 + q) & 3;
                    s += part[q][tid - 3 + tq];
                }
                u[cur ^ 1][tid] = s;
            } else if (tid == EW) {
                float s = 0.f;
                #pragma unroll
                for (int q = 0; q < 16; ++q) s += part[q][EW];
                u[cur ^ 1][tid] = s;
            }
            cur ^= 1;
        }
        lds_barrier();                    // publish u(l); vmcnt stays outstanding

        const float* U  = u[cur];
        const float* fb = A + rowcol_f;
        const float* An = A - (size_t)NB * plane;

        if (g < W4) {
            #pragma unroll
            for (int k = 0; k < K1; ++k) b1[k] = *(const float4*)(fb + roff[K0 + k]);
            float h0=0.f, h1=0.f, h2=0.f, h3=0.f, hw=0.f;
            if (rg == 0) {                // att row 0 = x row e (scalar x4 head)
                const float* hp = A + (size_t)e * NTOK + C + 4 * g;
                hw = U[EW];
                h0 = hp[0]; h1 = hp[1]; h2 = hp[2]; h3 = hp[3];
            }
            float4 acc = make_float4(0.f, 0.f, 0.f, 0.f);
            #pragma unroll
            for (int k = 0; k < K0; ++k) {
                const float w = U[rg + 16 * k + 2];
                acc.x += w * b0[k].x; acc.y += w * b0[k].y;
                acc.z += w * b0[k].z; acc.w += w * b0[k].w;
            }
            #pragma unroll
            for (int k = 0; k < K2; ++k) b2[k] = *(const float4*)(fb + roff[K0 + K1 + k]);
            #pragma unroll
            for (int k = 0; k < K1; ++k) {
                const float w = U[rg + 16 * (K0 + k) + 2];
                acc.x += w * b1[k].x; acc.y += w * b1[k].y;
                acc.z += w * b1[k].z; acc.w += w * b1[k].w;
            }
            #pragma unroll
            for (int k = 0; k < K2; ++k) {
                const float w = U[rg + 16 * (K0 + K1 + k) + 2];
                acc.x += w * b2[k].x; acc.y += w * b2[k].y;
                acc.z += w * b2[k].z; acc.w += w * b2[k].w;
            }
            if (rg == 0) {
                acc.x += hw * h0; acc.y += hw * h1;
                acc.z += hw * h2; acc.w += hw * h3;
            }
            *(float4*)&part[rg][4 * g] = acc;
            if (l > 0) {                  // issue next layer's chunk0 pre-barrier
                const float* fn = An + rowcol_f;
                #pragma unroll
                for (int k = 0; k < K0; ++k) b0[k] = *(const float4*)(fn + roff[k]);
            }
        } else if (g == W4) {             // the e-column (att col 0)
            const float* ep = A + rowcol_e;
            #pragma unroll
            for (int k = 0; k < K1; ++k) s1[k] = ep[roff[K0 + k]];
            float s = 0.f;
            if (rg == 0) s = U[EW] * A[(size_t)e * NTOK + e];
            #pragma unroll
            for (int k = 0; k < K0; ++k) s += U[rg + 16 * k + 2] * s0[k];
            #pragma unroll
            for (int k = 0; k < K2; ++k) s2[k] = ep[roff[K0 + K1 + k]];
            #pragma unroll
            for (int k = 0; k < K1; ++k) s += U[rg + 16 * (K0 + k) + 2] * s1[k];
            #pragma unroll
            for (int k = 0; k < K2; ++k) s += U[rg + 16 * (K0 + K1 + k) + 2] * s2[k];
            part[rg][EW] = s;
            if (l > 0) {
                const float* en = An + rowcol_e;
                #pragma unroll
                for (int k = 0; k < K0; ++k) s0[k] = en[roff[k]];
            }
        }
        lds_barrier();                    // publish part(l)
        A = An;
    }

    // final reduce (att cols 1..M-1 only; e-col excluded from argmax anyway)
    if (tid >= 3 && tid < M + 2) {
        float s = 0.f;
        #pragma unroll
        for (int q = 0; q < 16; ++q) {
            const int tq = (b + 2 * lo - 1 + q) & 3;
            s += part[q][tid - 3 + tq];
        }
        u[cur ^ 1][tid] = s;
    }
    cur ^= 1;
    __syncthreads();

    // max + argmax over p in [3, M+2); p ascending == att-col ascending
    if (tid < 256) {
        float v = -INFINITY; int idx = 0x7fffffff;
        if (tid >= 3 && tid < M + 2) { v = u[cur][tid]; idx = tid; }
        rv[tid] = v; rix[tid] = idx;
    }
    __syncthreads();
    for (int s = 128; s > 0; s >>= 1) {
        if (tid < s) {
            const float v2 = rv[tid + s]; const int i2 = rix[tid + s];
            if (v2 > rv[tid] || (v2 == rv[tid] && i2 < rix[tid])) {
                rv[tid] = v2; rix[tid] = i2;
            }
        }
        __syncthreads();
    }
    if (tid == 0) {
        out[e * NB + b]       = rv[0];
        out[640 + e * NB + b] = (float)(lo - 3 + rix[0]);   // = (j-1) + lo
    }
}

// bid = 128*e + b => bid%8 = b%8: all 5 chains of a batch on the SAME XCD
// (shared L2 dedups overlapping plane reads); 640 blocks, 2 blocks/CU.
__global__ __launch_bounds__(1024, 8) void part_att_kernel(
    const float* __restrict__ x, float* __restrict__ out)
{
    __shared__ float u[2][212];
    __shared__ float part[16][212];
    __shared__ float rv[256];
    __shared__ int   rix[256];

    const int bid = blockIdx.x;
    const int e   = bid >> 7;
    const int b   = bid & 127;
    const float* xb = x + (size_t)b * ((size_t)NTOK * NTOK);

    if (e < 2) {
        chain_pipe<197, 5, 4, 4>(xb, out, e, b, 5, u, part, rv, rix);
    } else {
        const int lo = (e == 2) ? 5 : (e == 3) ? 54 : 103;
        chain_pipe<99, 3, 2, 2>(xb, out, e, b, lo, u, part, rv, rix);
    }
}

extern "C" void kernel_launch(void* const* d_in, const int* in_sizes, int n_in,
                              void* d_out, int out_size, void* d_ws, size_t ws_size,
                              hipStream_t stream) {
    (void)in_sizes; (void)n_in; (void)d_ws; (void)ws_size; (void)out_size;
    const float* x = (const float*)d_in[0];
    float* out = (float*)d_out;
    part_att_kernel<<<dim3(640), dim3(1024), 0, stream>>>(x, out);
}

// Round 8
// 62.696 us; speedup vs baseline: 2.2768x; 1.4310x over previous
//
#include <hip/hip_runtime.h>

#define NB 128
#define NTOK 201
#define EW 210   // u-slot holding the att-col-0 (e-column) weight

// Publish LDS writes across a barrier WITHOUT draining vmcnt.
__device__ __forceinline__ void lds_barrier() {
    asm volatile("s_waitcnt lgkmcnt(0)" ::: "memory");
    __builtin_amdgcn_s_barrier();
}

// u^T <- u^T * att_e[l], l = 10..0, u0 = row 0 of att_e[11].
// 256 threads = 64 col-groups (g: 4 padded cols via float4) x 4 waves
// (w: rows r === w mod 4). Padded-col space p = xcol-(lo-3), valid [3,M+2),
// e-weight at u[EW]. Per-wave 16B-aligned start col C_w ((b+row+col)%4==0,
// row stride 4*201 === 0 mod 4); per-wave col shift undone in the reduce.
// Rows r >= M clamp in-class (r-4), auto-masked by zero weight u[r+2].
template<int M>
__device__ __forceinline__ void chain4(
    const float* __restrict__ xb, float* __restrict__ out,
    const int e, const int b, const int lo,
    float* u, float (*part)[212], float* rv, int* rix)
{
    constexpr int W4 = (M + 5) / 4;      // active float4 col-groups (50 / 26)
    constexpr int NK = (M + 3) / 4;      // rows per thread (50 / 25)

    const int tid = threadIdx.x;
    const int g   = tid & 63;
    const int w   = tid >> 6;            // wave index 0..3

    const size_t plane = (size_t)NTOK * NTOK;
    const float* L11 = xb + (size_t)(11 * NB) * plane + (size_t)e * NTOK;

    const int trg = (b + 2 * lo - 1 + w) & 3;
    const int C   = lo - trg;            // 16B-aligned start col for this wave

    // init u: zeros (clamp slots must stay 0), then valid slots
    if (tid < 212) u[tid] = 0.f;
    __syncthreads();
    if (tid >= 3 && tid < M + 2) u[tid] = L11[lo - 3 + tid];
    if (tid == EW)               u[tid] = L11[e];
    __syncthreads();

    const float* A = xb + (size_t)(10 * NB) * plane;
    for (int l = 10; l >= 0; --l) {
        if (g < W4) {
            float4 acc = make_float4(0.f, 0.f, 0.f, 0.f);
            if (w == 0) {                // att row 0 = x row e (head, wave 0 only)
                const float hw = u[EW];
                const float* hp = A + (size_t)e * NTOK + C + 4 * g;
                acc.x = hw * hp[0]; acc.y = hw * hp[1];
                acc.z = hw * hp[2]; acc.w = hw * hp[3];
            }
            const float* rp = A + (size_t)(lo - 1 + w) * NTOK + C + 4 * g;
            #pragma unroll
            for (int k = 0; k < NK - 1; ++k) {
                const float wt = u[w + 2 + 4 * k];
                const float4 a = *(const float4*)(rp + (size_t)(4 * NTOK) * k);
                acc.x += wt * a.x; acc.y += wt * a.y;
                acc.z += wt * a.z; acc.w += wt * a.w;
            }
            {   // tail row, in-class clamp for r >= M
                constexpr int k = NK - 1;
                const int r = w + 4 * k;
                const float wt = u[r + 2];
                const float4 a = *(const float4*)(rp + (size_t)(4 * NTOK) * k
                                                  - ((r >= M) ? 4 * NTOK : 0));
                acc.x += wt * a.x; acc.y += wt * a.y;
                acc.z += wt * a.z; acc.w += wt * a.w;
            }
            *(float4*)&part[w][4 * g] = acc;
        } else if (g == W4) {            // the e-column (att col 0)
            float s = 0.f;
            if (w == 0) s = u[EW] * A[(size_t)e * NTOK + e];
            const float* ep = A + (size_t)(lo - 1 + w) * NTOK + e;
            #pragma unroll
            for (int k = 0; k < NK - 1; ++k)
                s += u[w + 2 + 4 * k] * ep[(size_t)(4 * NTOK) * k];
            {
                constexpr int k = NK - 1;
                const int r = w + 4 * k;
                s += u[r + 2] * ep[(size_t)(4 * NTOK) * k - ((r >= M) ? 4 * NTOK : 0)];
            }
            part[w][EW] = s;
        }
        lds_barrier();                   // publish part
        // reduce 4 partials -> u (reads part, writes u: disjoint arrays)
        if (tid >= 3 && tid < M + 2) {
            float s = 0.f;
            #pragma unroll
            for (int q = 0; q < 4; ++q) {
                const int tq = (b + 2 * lo - 1 + q) & 3;
                s += part[q][tid - 3 + tq];   // undo per-wave col shift
            }
            u[tid] = s;
        } else if (tid == EW) {
            u[EW] = part[0][EW] + part[1][EW] + part[2][EW] + part[3][EW];
        }
        lds_barrier();                   // publish u / guard part reuse
        A -= (size_t)NB * plane;
    }

    // max + argmax over p in [3, M+2); p ascending == att-col ascending
    {
        float v = -INFINITY; int idx = 0x7fffffff;
        if (tid >= 3 && tid < M + 2) { v = u[tid]; idx = tid; }
        rv[tid] = v; rix[tid] = idx;
    }
    __syncthreads();
    for (int s = 128; s > 0; s >>= 1) {
        if (tid < s) {
            const float v2 = rv[tid + s]; const int i2 = rix[tid + s];
            if (v2 > rv[tid] || (v2 == rv[tid] && i2 < rix[tid])) {
                rv[tid] = v2; rix[tid] = i2;
            }
        }
        __syncthreads();
    }
    if (tid == 0) {
        out[e * NB + b]       = rv[0];
        out[640 + e * NB + b] = (float)(lo - 3 + rix[0]);   // = (j-1) + lo
    }
}

// bid = 128*e + b => bid%8 = b%8: all 5 chains of a batch on the SAME XCD
// (shared L2 dedups overlapping plane reads). 640 small blocks -> ~2.5
// independent chains/CU whose phases interleave (MLP across blocks).
__global__ __launch_bounds__(256, 4) void part_att_kernel(
    const float* __restrict__ x, float* __restrict__ out)
{
    __shared__ float u[212];
    __shared__ float part[4][212];
    __shared__ float rv[256];
    __shared__ int   rix[256];

    const int bid = blockIdx.x;
    const int e   = bid >> 7;
    const int b   = bid & 127;
    const float* xb = x + (size_t)b * ((size_t)NTOK * NTOK);

    if (e < 2) {
        chain4<197>(xb, out, e, b, 5, u, part, rv, rix);
    } else {
        const int lo = (e == 2) ? 5 : (e == 3) ? 54 : 103;
        chain4<99>(xb, out, e, b, lo, u, part, rv, rix);
    }
}

extern "C" void kernel_launch(void* const* d_in, const int* in_sizes, int n_in,
                              void* d_out, int out_size, void* d_ws, size_t ws_size,
                              hipStream_t stream) {
    (void)in_sizes; (void)n_in; (void)d_ws; (void)ws_size; (void)out_size;
    const float* x = (const float*)d_in[0];
    float* out = (float*)d_out;
    part_att_kernel<<<dim3(640), dim3(256), 0, stream>>>(x, out);
}